// Round 10
// baseline (1459.834 us; speedup 1.0000x reference)
//
#include <hip/hip_runtime.h>
#include <stdint.h>

using short8  = __attribute__((ext_vector_type(8))) short;
using floatx4 = __attribute__((ext_vector_type(4))) float;

typedef unsigned short u16;
typedef unsigned int u32;
typedef unsigned long long u64;

#define AS1(p) ((const __attribute__((address_space(1))) void*)(p))
#define AS3(p) ((__attribute__((address_space(3))) void*)(p))

__device__ __forceinline__ float bs2f(u16 u) { return __uint_as_float(((u32)u) << 16); }
__device__ __forceinline__ u16 f2bs(float f) {
  u32 x = __float_as_uint(f);
  x += 0x7FFFu + ((x >> 16) & 1u);   // RNE
  return (u16)(x >> 16);
}
__device__ __forceinline__ float lo16(u32 u) { return __uint_as_float(u << 16); }
__device__ __forceinline__ float hi16(u32 u) { return __uint_as_float(u & 0xFFFF0000u); }

// ---------------------------------------------------------------------------
// fp32 -> bf16 conversion for all 5 weight tensors in ONE launch.
// ---------------------------------------------------------------------------
__global__ __launch_bounds__(256) void cvt_all_k(
    const float* __restrict__ s0, const float* __restrict__ s1,
    const float* __restrict__ s2, const float* __restrict__ s3,
    const float* __restrict__ s4, u16* __restrict__ d0, u16* __restrict__ d1,
    u16* __restrict__ d2, u16* __restrict__ d3, u16* __restrict__ d4) {
  const int i = blockIdx.x * 256 + threadIdx.x;
  if (i < 131072)        d0[i] = f2bs(s0[i]);
  else if (i < 524288)   d1[i - 131072] = f2bs(s1[i - 131072]);
  else if (i < 655360)   d2[i - 524288] = f2bs(s2[i - 524288]);
  else if (i < 1179648)  d3[i - 655360] = f2bs(s3[i - 655360]);
  else                   d4[i - 1179648] = f2bs(s4[i - 1179648]);
}

// ---------------------------------------------------------------------------
// inp[row, r] = sum_k x[row, k] * Win[k, r]   (fp32, fmaf k-ascending)
// ---------------------------------------------------------------------------
__global__ __launch_bounds__(512) void inp_k(const float* __restrict__ x,
                                             const float* __restrict__ Win,
                                             float* __restrict__ inp) {
  const int row = blockIdx.x;
  const int r = threadIdx.x;
  const float* xr = x + (size_t)row * 8;
  float s = 0.f;
#pragma unroll
  for (int k = 0; k < 8; ++k) s = fmaf(Win[k * 512 + r], xr[k], s);
  inp[(size_t)row * 512 + r] = s;
}

// ---------------------------------------------------------------------------
// LIF reservoir, single-wave speculative: 32 blocks x 64 threads, lane c owns
// neurons 8c..8c+7. 8-step groups: fast path has NO ballot/branch/mask work
// (toggles accumulate in a per-lane flag); one ballot+branch per group. On a
// toggle (only during ~20-step ignition: reservoir saturates) the group is
// rolled back (saved v/ci/pz) and replayed with full per-step mask gathers.
// Both paths use the identical RN op sequence (bitwise-stable rounds 2-9).
// inp batch-loaded to registers per group, pinned by an asm memory barrier
// so the compiler cannot re-sink the prefetch (r7 failure mode).
// ---------------------------------------------------------------------------
__global__ __launch_bounds__(64, 1) void reservoir_k(
    const float* __restrict__ inp,  // [32,1024,512] fp32
    const float* __restrict__ Wres, // [512,512]
    u16* __restrict__ zout)         // [32,1024,512] bf16 (0.0/1.0, exact)
{
  const int b = blockIdx.x;
  const int c = threadIdx.x & 63;
  const float* ib = inp + (size_t)b * 524288 + c * 8;
  u16* zb = zout + (size_t)b * 524288 + c * 8;
  float v[8] = {}, ci[8] = {}, rec[8] = {};
  u32 pz = 0;
  for (int tb = 0; tb < 128; ++tb) {
    // batch-load this group's 8 steps of input currents (pinned below)
    float4 xa[8], xc[8];
#pragma unroll
    for (int u = 0; u < 8; ++u) {
      const float* p = ib + (size_t)(tb * 8 + u) * 512;
      xa[u] = *(const float4*)p;
      xc[u] = *(const float4*)(p + 4);
    }
    asm volatile("" ::: "memory");   // pin loads here; no sinking past this
    // save state for rollback
    float sv[8], sci[8];
#pragma unroll
    for (int j = 0; j < 8; ++j) { sv[j] = v[j]; sci[j] = ci[j]; }
    const u32 spz = pz;
    u32 togg = 0;
    // ---- fast path: no ballots, no branches, rec assumed constant ----
#pragma unroll
    for (int u = 0; u < 8; ++u) {
      const int t = tb * 8 + u;
      const float in[8] = {xa[u].x, xa[u].y, xa[u].z, xa[u].w,
                           xc[u].x, xc[u].y, xc[u].z, xc[u].w};
      u32 nzb = 0;
      u32 zw[4];
#pragma unroll
      for (int j = 0; j < 8; ++j) {
        const float vdec = __fadd_rn(v[j], __fmul_rn(0.004f, __fadd_rn(-v[j], ci[j])));
        const int zc = (__fadd_rn(vdec, -0.1f) > 0.f) ? 1 : 0;
        v[j] = zc ? 0.f : vdec;
        nzb |= (u32)zc << j;
        ci[j] = __fadd_rn(__fmul_rn(ci[j], 0.8f), __fadd_rn(in[j], rec[j]));
        if (j & 1) zw[j >> 1] |= zc ? 0x3F800000u : 0u;
        else       zw[j >> 1]  = zc ? 0x3F80u : 0u;
      }
      *(uint4*)(zb + (size_t)t * 512) = make_uint4(zw[0], zw[1], zw[2], zw[3]);
      togg |= nzb ^ pz;
      pz = nzb;
    }
    const u64 anyt = __ballot(togg != 0);
    if (anyt) {
      // ---- rollback & replay with per-step toggle processing (rare) ----
#pragma unroll
      for (int j = 0; j < 8; ++j) { v[j] = sv[j]; ci[j] = sci[j]; }
      pz = spz;
#pragma unroll 1
      for (int u = 0; u < 8; ++u) {
        const int t = tb * 8 + u;
        const float in[8] = {xa[u].x, xa[u].y, xa[u].z, xa[u].w,
                             xc[u].x, xc[u].y, xc[u].z, xc[u].w};
        u32 nzb = 0;
        u32 zw[4];
#pragma unroll
        for (int j = 0; j < 8; ++j) {
          const float vdec = __fadd_rn(v[j], __fmul_rn(0.004f, __fadd_rn(-v[j], ci[j])));
          const int zc = (__fadd_rn(vdec, -0.1f) > 0.f) ? 1 : 0;
          v[j] = zc ? 0.f : vdec;
          nzb |= (u32)zc << j;
          ci[j] = __fadd_rn(__fmul_rn(ci[j], 0.8f), __fadd_rn(in[j], rec[j]));
          if (j & 1) zw[j >> 1] |= zc ? 0x3F800000u : 0u;
          else       zw[j >> 1]  = zc ? 0x3F80u : 0u;
        }
        *(uint4*)(zb + (size_t)t * 512) = make_uint4(zw[0], zw[1], zw[2], zw[3]);
        const u64 a2 = __ballot((nzb ^ pz) != 0);
        if (a2) {
#pragma unroll
          for (int j = 0; j < 8; ++j) {
            const u64 nm = __ballot((nzb >> j) & 1);
            const u64 pm = __ballot((pz >> j) & 1);
            u64 on   = nm & ~pm;
            u64 offm = pm & ~nm;
            while (on) {
              const int cc = __builtin_ctzll(on); on &= on - 1;
              const float* wr = Wres + ((size_t)(cc * 8 + j) << 9) + c * 8;
              const float4 w0 = *(const float4*)wr;
              const float4 w1 = *(const float4*)(wr + 4);
              rec[0] += w0.x; rec[1] += w0.y; rec[2] += w0.z; rec[3] += w0.w;
              rec[4] += w1.x; rec[5] += w1.y; rec[6] += w1.z; rec[7] += w1.w;
            }
            while (offm) {
              const int cc = __builtin_ctzll(offm); offm &= offm - 1;
              const float* wr = Wres + ((size_t)(cc * 8 + j) << 9) + c * 8;
              const float4 w0 = *(const float4*)wr;
              const float4 w1 = *(const float4*)(wr + 4);
              rec[0] -= w0.x; rec[1] -= w0.y; rec[2] -= w0.z; rec[3] -= w0.w;
              rec[4] -= w1.x; rec[5] -= w1.y; rec[6] -= w1.z; rec[7] -= w1.w;
            }
          }
        }
        pz = nzb;
      }
    }
  }
}

// ---------------------------------------------------------------------------
// Generic bf16 MFMA GEMM: C = epilogue(A @ B^T * scale + bias)
// ---------------------------------------------------------------------------
enum { MODE_BF16 = 0, MODE_F32 = 1, MODE_DUAL = 2, MODE_QKV = 3 };

template <int WM, int WN, int MODE>
__global__ __launch_bounds__(WM * WN * 64) void gemm_bt(
    const u16* __restrict__ A, const u16* __restrict__ B,
    const float* __restrict__ bias, void* __restrict__ C0,
    void* __restrict__ C1, void* __restrict__ C2, int K, int lda, int ldb,
    int ldc, long long sA, long long sB, long long sC, float scale, int relu)
{
  constexpr int BM = WM * 64, BN = WN * 64, BK = 32;
  constexpr int NT = WM * WN * 64;
  constexpr int CA = BM * 4 / NT, CB = BN * 4 / NT;
  __shared__ __align__(16) u16 As[BM * BK];
  __shared__ __align__(16) u16 Bs[BN * BK];
  const int tid = threadIdx.x;
  const int bz = blockIdx.z;
  const u16* Ab = A + (size_t)bz * sA + (size_t)blockIdx.y * BM * lda;
  const u16* Bb = B + (size_t)bz * sB + (size_t)blockIdx.x * BN * ldb;
  const int wavei = tid >> 6, lane = tid & 63;
  const int r16 = lane & 15, quad = lane >> 4;
  const int wm = (wavei % WM) * 64, wn = (wavei / WM) * 64;
  floatx4 acc[4][4] = {};
  for (int k0 = 0; k0 < K; k0 += BK) {
#pragma unroll
    for (int c = 0; c < CA; ++c) {
      const int idx = c * NT + tid;
      const int row = idx >> 2, kc = (idx & 3) << 3;
      __builtin_amdgcn_global_load_lds(AS1(Ab + (size_t)row * lda + k0 + kc),
                                       AS3(As + idx * 8), 16, 0, 0);
    }
#pragma unroll
    for (int c = 0; c < CB; ++c) {
      const int idx = c * NT + tid;
      const int row = idx >> 2, kc = (idx & 3) << 3;
      __builtin_amdgcn_global_load_lds(AS1(Bb + (size_t)row * ldb + k0 + kc),
                                       AS3(Bs + idx * 8), 16, 0, 0);
    }
    __syncthreads();
    short8 af[4], bfr[4];
#pragma unroll
    for (int i = 0; i < 4; ++i)
      af[i] = *(const short8*)&As[(wm + i * 16 + r16) * BK + quad * 8];
#pragma unroll
    for (int i = 0; i < 4; ++i)
      bfr[i] = *(const short8*)&Bs[(wn + i * 16 + r16) * BK + quad * 8];
#pragma unroll
    for (int i = 0; i < 4; ++i)
#pragma unroll
      for (int j = 0; j < 4; ++j)
        acc[i][j] = __builtin_amdgcn_mfma_f32_16x16x32_bf16(af[i], bfr[j], acc[i][j], 0, 0, 0);
    __syncthreads();
  }
#pragma unroll
  for (int i = 0; i < 4; ++i) {
#pragma unroll
    for (int j = 0; j < 4; ++j) {
#pragma unroll
      for (int q = 0; q < 4; ++q) {
        const int m = blockIdx.y * BM + wm + i * 16 + quad * 4 + q;
        const int n = blockIdx.x * BN + wn + j * 16 + r16;
        float val = acc[i][j][q] * scale;
        if (bias) val += bias[n];
        if (relu) val = fmaxf(val, 0.f);
        if constexpr (MODE == MODE_BF16) {
          ((u16*)C0)[(size_t)bz * sC + (size_t)m * ldc + n] = f2bs(val);
        } else if constexpr (MODE == MODE_F32) {
          ((float*)C0)[(size_t)m * ldc + n] = val;
        } else if constexpr (MODE == MODE_DUAL) {
          ((float*)C0)[(size_t)m * ldc + n] = val;
          ((u16*)C1)[(size_t)m * ldc + n] = f2bs(val);
        } else if constexpr (MODE == MODE_QKV) {
          const int b = m >> 10, s = m & 1023;
          const u16 outv = f2bs(val);
          const int h = (n & 255) >> 6, d = n & 63;
          if (n < 256)
            ((u16*)C0)[(((size_t)(b * 4 + h)) * 1024 + s) * 64 + d] = outv;  // q [BH,S,dh]
          else if (n < 512)
            ((u16*)C1)[(((size_t)(b * 4 + h)) * 1024 + s) * 64 + d] = outv;  // k [BH,S,dh]
          else
            ((u16*)C2)[(((size_t)(b * 4 + h)) * 64 + d) * 1024 + s] = outv;  // v^T [BH,dh,S]
        }
      }
    }
  }
}

// ---------------------------------------------------------------------------
// Flash attention: one block per (q-tile 128, pair). 4 waves x 32 q-rows.
// ---------------------------------------------------------------------------
__global__ __launch_bounds__(256) void attn_k(
    const u16* __restrict__ q_s,  // [128,1024,64]
    const u16* __restrict__ k_s,  // [128,1024,64]
    const u16* __restrict__ v_t,  // [128,64,1024]
    u16* __restrict__ o16)        // [32768,256] merged
{
  constexpr int LQ = 72, LV = 136, LP = 136;
  __shared__ __align__(16) u16 Qs[128 * LQ];
  __shared__ __align__(16) u16 Ks[128 * LQ];
  __shared__ __align__(16) u16 Vt[64 * LV];
  __shared__ __align__(16) u16 Ps[128 * LP];
  const int tid = threadIdx.x;
  const int w = tid >> 6, lane = tid & 63;
  const int r16 = lane & 15, quad = lane >> 4;
  const int p = blockIdx.y;
  const int q0 = blockIdx.x * 128;
  const u16* qg = q_s + ((size_t)p * 1024 + q0) * 64;
  const u16* kg = k_s + (size_t)p * 65536;
  const u16* vg = v_t + (size_t)p * 65536;

#pragma unroll
  for (int it = 0; it < 4; ++it) {
    const int idx = it * 256 + tid;
    const int row = idx >> 3, c8 = (idx & 7) * 8;
    *(uint4*)&Qs[row * LQ + c8] = *(const uint4*)(qg + (size_t)row * 64 + c8);
    *(uint4*)&Ks[row * LQ + c8] = *(const uint4*)(kg + (size_t)row * 64 + c8);
  }
#pragma unroll
  for (int it = 0; it < 4; ++it) {
    const int idx = it * 256 + tid;
    const int row = idx >> 4, c8 = (idx & 15) * 8;
    *(uint4*)&Vt[row * LV + c8] = *(const uint4*)(vg + (size_t)row * 1024 + c8);
  }
  __syncthreads();

  short8 aq[2][2];
#pragma unroll
  for (int i = 0; i < 2; ++i)
#pragma unroll
    for (int kc = 0; kc < 2; ++kc)
      aq[i][kc] = *(const short8*)&Qs[(w * 32 + i * 16 + r16) * LQ + kc * 32 + quad * 8];

  floatx4 o[2][4] = {};
  float mr[2][4], l[2][4];
#pragma unroll
  for (int i = 0; i < 2; ++i)
#pragma unroll
    for (int q = 0; q < 4; ++q) { mr[i][q] = -3e38f; l[i][q] = 0.f; }

  for (int kt = 0; kt < 8; ++kt) {
    uint4 kpre[4], vpre[4];
    if (kt < 7) {
      const u16* kgn = kg + (size_t)(kt + 1) * 128 * 64;
#pragma unroll
      for (int it = 0; it < 4; ++it) {
        const int idx = it * 256 + tid;
        kpre[it] = *(const uint4*)(kgn + (size_t)(idx >> 3) * 64 + (idx & 7) * 8);
        vpre[it] = *(const uint4*)(vg + (size_t)(idx >> 4) * 1024 + (kt + 1) * 128 + (idx & 15) * 8);
      }
    }
    floatx4 s[2][8] = {};
#pragma unroll
    for (int kc = 0; kc < 2; ++kc) {
#pragma unroll
      for (int f = 0; f < 8; ++f) {
        const short8 bk = *(const short8*)&Ks[(f * 16 + r16) * LQ + kc * 32 + quad * 8];
#pragma unroll
        for (int i = 0; i < 2; ++i)
          s[i][f] = __builtin_amdgcn_mfma_f32_16x16x32_bf16(aq[i][kc], bk, s[i][f], 0, 0, 0);
      }
    }
#pragma unroll
    for (int i = 0; i < 2; ++i) {
      float mt[4] = {-3e38f, -3e38f, -3e38f, -3e38f};
#pragma unroll
      for (int f = 0; f < 8; ++f)
#pragma unroll
        for (int q = 0; q < 4; ++q) {
          s[i][f][q] *= 0.125f;
          mt[q] = fmaxf(mt[q], s[i][f][q]);
        }
#pragma unroll
      for (int off = 8; off > 0; off >>= 1)
#pragma unroll
        for (int q = 0; q < 4; ++q) mt[q] = fmaxf(mt[q], __shfl_xor(mt[q], off));
      float al[4], rs[4] = {};
#pragma unroll
      for (int q = 0; q < 4; ++q) {
        const float mn = fmaxf(mr[i][q], mt[q]);
        al[q] = __expf(mr[i][q] - mn);
        mr[i][q] = mn;
      }
#pragma unroll
      for (int f = 0; f < 8; ++f)
#pragma unroll
        for (int q = 0; q < 4; ++q) {
          const float pv = __expf(s[i][f][q] - mr[i][q]);
          s[i][f][q] = pv;
          rs[q] += pv;
        }
#pragma unroll
      for (int off = 8; off > 0; off >>= 1)
#pragma unroll
        for (int q = 0; q < 4; ++q) rs[q] += __shfl_xor(rs[q], off);
#pragma unroll
      for (int q = 0; q < 4; ++q) l[i][q] = l[i][q] * al[q] + rs[q];
#pragma unroll
      for (int n = 0; n < 4; ++n)
#pragma unroll
        for (int q = 0; q < 4; ++q) o[i][n][q] *= al[q];
#pragma unroll
      for (int f = 0; f < 8; ++f)
#pragma unroll
        for (int q = 0; q < 4; ++q)
          Ps[(w * 32 + i * 16 + quad * 4 + q) * LP + f * 16 + r16] = f2bs(s[i][f][q]);
    }
#pragma unroll
    for (int kc = 0; kc < 4; ++kc) {
      short8 ap[2];
#pragma unroll
      for (int i = 0; i < 2; ++i)
        ap[i] = *(const short8*)&Ps[(w * 32 + i * 16 + r16) * LP + kc * 32 + quad * 8];
#pragma unroll
      for (int n = 0; n < 4; ++n) {
        const short8 bv = *(const short8*)&Vt[(n * 16 + r16) * LV + kc * 32 + quad * 8];
#pragma unroll
        for (int i = 0; i < 2; ++i)
          o[i][n] = __builtin_amdgcn_mfma_f32_16x16x32_bf16(ap[i], bv, o[i][n], 0, 0, 0);
      }
    }
    __syncthreads();
    if (kt < 7) {
#pragma unroll
      for (int it = 0; it < 4; ++it) {
        const int idx = it * 256 + tid;
        *(uint4*)&Ks[(idx >> 3) * LQ + (idx & 7) * 8] = kpre[it];
        *(uint4*)&Vt[(idx >> 4) * LV + (idx & 15) * 8] = vpre[it];
      }
      __syncthreads();
    }
  }
  const int bb = p >> 2, hh = p & 3;
#pragma unroll
  for (int i = 0; i < 2; ++i)
#pragma unroll
    for (int q = 0; q < 4; ++q) {
      const float inv = 1.f / l[i][q];
      const int srow = q0 + w * 32 + i * 16 + quad * 4 + q;
#pragma unroll
      for (int n = 0; n < 4; ++n)
        o16[((size_t)bb * 1024 + srow) * 256 + hh * 64 + n * 16 + r16] =
            f2bs(o[i][n][q] * inv);
    }
}

// ---------------------------------------------------------------------------
// Fused residual-add + LayerNorm over 256 fp32; writes fp32 and/or bf16.
// ---------------------------------------------------------------------------
__global__ __launch_bounds__(256) void ln_k(const float* __restrict__ x,
                                            const float* __restrict__ add,
                                            const float* __restrict__ g,
                                            const float* __restrict__ bta,
                                            float* __restrict__ y32,
                                            u16* __restrict__ y16) {
  const int row = blockIdx.x * 4 + (threadIdx.x >> 6);
  const int lane = threadIdx.x & 63;
  const size_t base = (size_t)row * 256 + lane * 4;
  const float4 xv = *(const float4*)(x + base);
  const float4 av = *(const float4*)(add + base);
  float sv[4] = {xv.x + av.x, xv.y + av.y, xv.z + av.z, xv.w + av.w};
  float sum = sv[0] + sv[1] + sv[2] + sv[3];
#pragma unroll
  for (int off = 32; off > 0; off >>= 1) sum += __shfl_xor(sum, off);
  const float mean = sum * (1.f / 256.f);
  float var = 0.f;
  float d[4];
#pragma unroll
  for (int i = 0; i < 4; ++i) { d[i] = sv[i] - mean; var += d[i] * d[i]; }
#pragma unroll
  for (int off = 32; off > 0; off >>= 1) var += __shfl_xor(var, off);
  var *= (1.f / 256.f);
  const float inv = 1.f / sqrtf(var + 1e-5f);
  float yv[4];
#pragma unroll
  for (int i = 0; i < 4; ++i)
    yv[i] = d[i] * inv * g[lane * 4 + i] + bta[lane * 4 + i];
  if (y32) *(float4*)(y32 + base) = make_float4(yv[0], yv[1], yv[2], yv[3]);
  if (y16) {
    const u32 p0 = (u32)f2bs(yv[0]) | ((u32)f2bs(yv[1]) << 16);
    const u32 p1 = (u32)f2bs(yv[2]) | ((u32)f2bs(yv[3]) << 16);
    *(uint2*)(y16 + base) = make_uint2(p0, p1);
  }
}

// ---------------------------------------------------------------------------
extern "C" void kernel_launch(void* const* d_in, const int* in_sizes, int n_in,
                              void* d_out, int out_size, void* d_ws,
                              size_t ws_size, hipStream_t stream) {
  (void)in_sizes; (void)n_in; (void)out_size; (void)ws_size;
  const float* x     = (const float*)d_in[0];
  const float* Win   = (const float*)d_in[1];
  const float* Wres  = (const float*)d_in[2];
  const float* Wread = (const float*)d_in[3];
  const float* bread = (const float*)d_in[4];
  const float* Wqkv  = (const float*)d_in[5];
  const float* bqkv  = (const float*)d_in[6];
  const float* Wo    = (const float*)d_in[7];
  const float* bo    = (const float*)d_in[8];
  const float* g1    = (const float*)d_in[9];
  const float* b1    = (const float*)d_in[10];
  const float* g2    = (const float*)d_in[11];
  const float* b2    = (const float*)d_in[12];
  const float* W1    = (const float*)d_in[13];
  const float* c1    = (const float*)d_in[14];
  const float* W2    = (const float*)d_in[15];
  const float* c2    = (const float*)d_in[16];

  char* ws = (char*)d_ws;
  size_t off = 0;
  auto carve = [&](size_t bytes) {
    char* p = ws + off;
    off += (bytes + 255) & ~(size_t)255;
    return p;
  };
  u16* z      = (u16*)carve((size_t)32 * 1024 * 512 * 2);
  u16* wrd16  = (u16*)carve((size_t)256 * 512 * 2);
  u16* wqkv16 = (u16*)carve((size_t)2 * 768 * 256 * 2);
  u16* wo16   = (u16*)carve((size_t)2 * 256 * 256 * 2);
  u16* w116   = (u16*)carve((size_t)2 * 1024 * 256 * 2);
  u16* w216   = (u16*)carve((size_t)2 * 256 * 1024 * 2);
  u16* q_s    = (u16*)carve((size_t)128 * 1024 * 64 * 2);
  u16* k_s    = (u16*)carve((size_t)128 * 1024 * 64 * 2);
  u16* v_t    = (u16*)carve((size_t)128 * 64 * 1024 * 2);
  float* h32  = (float*)carve((size_t)32768 * 256 * 4);
  float* lin  = (float*)carve((size_t)32768 * 256 * 4);
  u16* h16    = (u16*)carve((size_t)32768 * 256 * 2);
  u16* ff1    = (u16*)carve((size_t)32768 * 1024 * 2);
  u16* o16    = h16;          // attention output reuses h16
  float* inp  = (float*)ff1;  // precomputed input currents (dead before ff1)

  cvt_all_k<<<dim3(6656), dim3(256), 0, stream>>>(Wread, Wqkv, Wo, W1, W2,
                                                  wrd16, wqkv16, wo16, w116,
                                                  w216);
  inp_k<<<dim3(32768), dim3(512), 0, stream>>>(x, Win, inp);
  reservoir_k<<<dim3(32), dim3(64), 0, stream>>>(inp, Wres, z);

  // readout: h = z @ Wread^T + bread  (dual fp32 + bf16)
  gemm_bt<2, 2, MODE_DUAL><<<dim3(2, 256, 1), dim3(256), 0, stream>>>(
      z, wrd16, bread, h32, h16, nullptr, 512, 512, 512, 256, 0, 0, 0, 1.0f, 0);

  for (int l = 0; l < 2; ++l) {
    gemm_bt<2, 2, MODE_QKV><<<dim3(6, 256, 1), dim3(256), 0, stream>>>(
        h16, wqkv16 + (size_t)l * 196608, bqkv + l * 768, q_s, k_s, v_t, 256,
        256, 256, 0, 0, 0, 0, 1.0f, 0);
    attn_k<<<dim3(8, 128), dim3(256), 0, stream>>>(q_s, k_s, v_t, o16);
    gemm_bt<2, 2, MODE_F32><<<dim3(2, 256, 1), dim3(256), 0, stream>>>(
        o16, wo16 + (size_t)l * 65536, bo + l * 256, lin, nullptr, nullptr,
        256, 256, 256, 256, 0, 0, 0, 1.0f, 0);
    ln_k<<<dim3(8192), dim3(256), 0, stream>>>(h32, lin, g1 + l * 256,
                                               b1 + l * 256, h32, h16);
    gemm_bt<2, 2, MODE_BF16><<<dim3(8, 256, 1), dim3(256), 0, stream>>>(
        h16, w116 + (size_t)l * 262144, c1 + l * 1024, ff1, nullptr, nullptr,
        256, 256, 256, 1024, 0, 0, 0, 1.0f, 1);
    gemm_bt<2, 2, MODE_F32><<<dim3(2, 256, 1), dim3(256), 0, stream>>>(
        ff1, w216 + (size_t)l * 262144, c2 + l * 256, lin, nullptr, nullptr,
        1024, 1024, 1024, 256, 0, 0, 0, 1.0f, 0);
    float* y32 = (l == 1) ? (float*)d_out : h32;
    u16* y16 = (l == 1) ? nullptr : h16;
    ln_k<<<dim3(8192), dim3(256), 0, stream>>>(h32, lin, g2 + l * 256,
                                               b2 + l * 256, y32, y16);
  }
}

// Round 11
// 1372.665 us; speedup vs baseline: 1.0635x; 1.0635x over previous
//
#include <hip/hip_runtime.h>
#include <stdint.h>

using short8  = __attribute__((ext_vector_type(8))) short;
using floatx4 = __attribute__((ext_vector_type(4))) float;

typedef unsigned short u16;
typedef unsigned int u32;
typedef unsigned long long u64;

#define AS1(p) ((const __attribute__((address_space(1))) void*)(p))
#define AS3(p) ((__attribute__((address_space(3))) void*)(p))

__device__ __forceinline__ float bs2f(u16 u) { return __uint_as_float(((u32)u) << 16); }
__device__ __forceinline__ u16 f2bs(float f) {
  u32 x = __float_as_uint(f);
  x += 0x7FFFu + ((x >> 16) & 1u);   // RNE
  return (u16)(x >> 16);
}
__device__ __forceinline__ float lo16(u32 u) { return __uint_as_float(u << 16); }
__device__ __forceinline__ float hi16(u32 u) { return __uint_as_float(u & 0xFFFF0000u); }

// ---------------------------------------------------------------------------
// fp32 -> bf16 conversion for all 5 weight tensors in ONE launch.
// ---------------------------------------------------------------------------
__global__ __launch_bounds__(256) void cvt_all_k(
    const float* __restrict__ s0, const float* __restrict__ s1,
    const float* __restrict__ s2, const float* __restrict__ s3,
    const float* __restrict__ s4, u16* __restrict__ d0, u16* __restrict__ d1,
    u16* __restrict__ d2, u16* __restrict__ d3, u16* __restrict__ d4) {
  const int i = blockIdx.x * 256 + threadIdx.x;
  if (i < 131072)        d0[i] = f2bs(s0[i]);
  else if (i < 524288)   d1[i - 131072] = f2bs(s1[i - 131072]);
  else if (i < 655360)   d2[i - 524288] = f2bs(s2[i - 524288]);
  else if (i < 1179648)  d3[i - 655360] = f2bs(s3[i - 655360]);
  else                   d4[i - 1179648] = f2bs(s4[i - 1179648]);
}

// ---------------------------------------------------------------------------
// inp[row, idx(r)] = sum_k x[row, k] * Win[k, r]   (fp32, fmaf k-ascending —
// same compute as before, stored in the reservoir's LDS-staging layout:
// per step, plane0 = lane-major neurons 8c..8c+3, plane1 = neurons 8c+4..8c+7
// so both ds_read_b128s in the reservoir have 16B lane stride (conflict-free)
// and global_load_lds's lane-linear write matches the layout exactly.
// ---------------------------------------------------------------------------
__global__ __launch_bounds__(512) void inp_k(const float* __restrict__ x,
                                             const float* __restrict__ Win,
                                             float* __restrict__ inp) {
  const int row = blockIdx.x;
  const int r = threadIdx.x;
  const float* xr = x + (size_t)row * 8;
  float s = 0.f;
#pragma unroll
  for (int k = 0; k < 8; ++k) s = fmaf(Win[k * 512 + r], xr[k], s);
  const int c = r >> 3, j = r & 7;
  const int idx = (j < 4) ? (c * 4 + j) : (256 + c * 4 + (j - 4));
  inp[(size_t)row * 512 + idx] = s;
}

// ---------------------------------------------------------------------------
// LIF reservoir, single-wave: 32 blocks x 64 threads, lane c owns neurons
// 8c..8c+7. inp staged through DOUBLE-BUFFERED LDS tiles of 8 steps (16 KB,
// 16 x global_load_lds width-16 — compiler cannot sink these, r8/r10's
// failure mode) with s_waitcnt vmcnt(16): tile g drains while tile g+1 stays
// in flight, hidden under the previous group's ~1400 VALU cycles.
// Step body: r8's exact RN op sequence (bitwise-stable rounds 2-10), one
// ballot/step, full mask reconstruction only on (rare) toggles. No barriers.
// ---------------------------------------------------------------------------
__global__ __launch_bounds__(64, 1) void reservoir_k(
    const float* __restrict__ inp,  // [32,1024,512] fp32, interleaved layout
    const float* __restrict__ Wres, // [512,512]
    u16* __restrict__ zout)         // [32,1024,512] bf16 (0.0/1.0, exact)
{
  const int b = blockIdx.x;
  const int c = threadIdx.x & 63;
  __shared__ __align__(16) float s_in[2][4096];   // 2 x (8 steps x 512)
  const float* ib = inp + (size_t)b * 524288;
  u16* zb = zout + (size_t)b * 524288 + c * 8;
  float v[8] = {}, ci[8] = {}, rec[8] = {};
  u32 pz = 0;
  // prime the pipeline: tiles 0 and 1
#pragma unroll
  for (int i = 0; i < 16; ++i)
    __builtin_amdgcn_global_load_lds(AS1(ib + i * 256 + c * 4),
                                     AS3(&s_in[0][i * 256 + c * 4]), 16, 0, 0);
#pragma unroll
  for (int i = 0; i < 16; ++i)
    __builtin_amdgcn_global_load_lds(AS1(ib + 4096 + i * 256 + c * 4),
                                     AS3(&s_in[1][i * 256 + c * 4]), 16, 0, 0);
  for (int g = 0; g < 128; ++g) {
    const int buf = g & 1;
    if (g < 126) __builtin_amdgcn_s_waitcnt(0x4F70);  // vmcnt(16): tile g in
    else         __builtin_amdgcn_s_waitcnt(0x0F70);  // vmcnt(0): last tiles
    asm volatile("" ::: "memory");                    // no ds_read hoisting
#pragma unroll
    for (int u = 0; u < 8; ++u) {
      const int t = g * 8 + u;
      const float4 xa = *(const float4*)&s_in[buf][u * 512 + c * 4];
      const float4 xc = *(const float4*)&s_in[buf][u * 512 + 256 + c * 4];
      const float in[8] = {xa.x, xa.y, xa.z, xa.w, xc.x, xc.y, xc.z, xc.w};
      u32 nzb = 0;
      u32 zw[4];
#pragma unroll
      for (int j = 0; j < 8; ++j) {
        const float vdec = __fadd_rn(v[j], __fmul_rn(0.004f, __fadd_rn(-v[j], ci[j])));
        const int zc = (__fadd_rn(vdec, -0.1f) > 0.f) ? 1 : 0;
        v[j] = zc ? 0.f : vdec;
        nzb |= (u32)zc << j;
        ci[j] = __fadd_rn(__fmul_rn(ci[j], 0.8f), __fadd_rn(in[j], rec[j]));
        if (j & 1) zw[j >> 1] |= zc ? 0x3F800000u : 0u;
        else       zw[j >> 1]  = zc ? 0x3F80u : 0u;
      }
      *(uint4*)(zb + (size_t)t * 512) = make_uint4(zw[0], zw[1], zw[2], zw[3]);
      const u64 anyt = __ballot((nzb ^ pz) != 0);
      if (anyt) {                    // uniform branch; rare after ignition
#pragma unroll
        for (int j = 0; j < 8; ++j) {
          const u64 nm = __ballot((nzb >> j) & 1);
          const u64 pm = __ballot((pz >> j) & 1);
          u64 on   = nm & ~pm;
          u64 offm = pm & ~nm;
          while (on) {
            const int cc = __builtin_ctzll(on); on &= on - 1;
            const float* wr = Wres + ((size_t)(cc * 8 + j) << 9) + c * 8;
            const float4 w0 = *(const float4*)wr;
            const float4 w1 = *(const float4*)(wr + 4);
            rec[0] += w0.x; rec[1] += w0.y; rec[2] += w0.z; rec[3] += w0.w;
            rec[4] += w1.x; rec[5] += w1.y; rec[6] += w1.z; rec[7] += w1.w;
          }
          while (offm) {
            const int cc = __builtin_ctzll(offm); offm &= offm - 1;
            const float* wr = Wres + ((size_t)(cc * 8 + j) << 9) + c * 8;
            const float4 w0 = *(const float4*)wr;
            const float4 w1 = *(const float4*)(wr + 4);
            rec[0] -= w0.x; rec[1] -= w0.y; rec[2] -= w0.z; rec[3] -= w0.w;
            rec[4] -= w1.x; rec[5] -= w1.y; rec[6] -= w1.z; rec[7] -= w1.w;
          }
        }
      }
      pz = nzb;
    }
    asm volatile("" ::: "memory");                    // reads done before refill
    if (g + 2 < 128) {
      const float* gt = ib + (size_t)(g + 2) * 4096;
#pragma unroll
      for (int i = 0; i < 16; ++i)
        __builtin_amdgcn_global_load_lds(AS1(gt + i * 256 + c * 4),
                                         AS3(&s_in[buf][i * 256 + c * 4]), 16, 0, 0);
    }
  }
}

// ---------------------------------------------------------------------------
// Generic bf16 MFMA GEMM: C = epilogue(A @ B^T * scale + bias)
// ---------------------------------------------------------------------------
enum { MODE_BF16 = 0, MODE_F32 = 1, MODE_DUAL = 2, MODE_QKV = 3 };

template <int WM, int WN, int MODE>
__global__ __launch_bounds__(WM * WN * 64) void gemm_bt(
    const u16* __restrict__ A, const u16* __restrict__ B,
    const float* __restrict__ bias, void* __restrict__ C0,
    void* __restrict__ C1, void* __restrict__ C2, int K, int lda, int ldb,
    int ldc, long long sA, long long sB, long long sC, float scale, int relu)
{
  constexpr int BM = WM * 64, BN = WN * 64, BK = 32;
  constexpr int NT = WM * WN * 64;
  constexpr int CA = BM * 4 / NT, CB = BN * 4 / NT;
  __shared__ __align__(16) u16 As[BM * BK];
  __shared__ __align__(16) u16 Bs[BN * BK];
  const int tid = threadIdx.x;
  const int bz = blockIdx.z;
  const u16* Ab = A + (size_t)bz * sA + (size_t)blockIdx.y * BM * lda;
  const u16* Bb = B + (size_t)bz * sB + (size_t)blockIdx.x * BN * ldb;
  const int wavei = tid >> 6, lane = tid & 63;
  const int r16 = lane & 15, quad = lane >> 4;
  const int wm = (wavei % WM) * 64, wn = (wavei / WM) * 64;
  floatx4 acc[4][4] = {};
  for (int k0 = 0; k0 < K; k0 += BK) {
#pragma unroll
    for (int c = 0; c < CA; ++c) {
      const int idx = c * NT + tid;
      const int row = idx >> 2, kc = (idx & 3) << 3;
      __builtin_amdgcn_global_load_lds(AS1(Ab + (size_t)row * lda + k0 + kc),
                                       AS3(As + idx * 8), 16, 0, 0);
    }
#pragma unroll
    for (int c = 0; c < CB; ++c) {
      const int idx = c * NT + tid;
      const int row = idx >> 2, kc = (idx & 3) << 3;
      __builtin_amdgcn_global_load_lds(AS1(Bb + (size_t)row * ldb + k0 + kc),
                                       AS3(Bs + idx * 8), 16, 0, 0);
    }
    __syncthreads();
    short8 af[4], bfr[4];
#pragma unroll
    for (int i = 0; i < 4; ++i)
      af[i] = *(const short8*)&As[(wm + i * 16 + r16) * BK + quad * 8];
#pragma unroll
    for (int i = 0; i < 4; ++i)
      bfr[i] = *(const short8*)&Bs[(wn + i * 16 + r16) * BK + quad * 8];
#pragma unroll
    for (int i = 0; i < 4; ++i)
#pragma unroll
      for (int j = 0; j < 4; ++j)
        acc[i][j] = __builtin_amdgcn_mfma_f32_16x16x32_bf16(af[i], bfr[j], acc[i][j], 0, 0, 0);
    __syncthreads();
  }
#pragma unroll
  for (int i = 0; i < 4; ++i) {
#pragma unroll
    for (int j = 0; j < 4; ++j) {
#pragma unroll
      for (int q = 0; q < 4; ++q) {
        const int m = blockIdx.y * BM + wm + i * 16 + quad * 4 + q;
        const int n = blockIdx.x * BN + wn + j * 16 + r16;
        float val = acc[i][j][q] * scale;
        if (bias) val += bias[n];
        if (relu) val = fmaxf(val, 0.f);
        if constexpr (MODE == MODE_BF16) {
          ((u16*)C0)[(size_t)bz * sC + (size_t)m * ldc + n] = f2bs(val);
        } else if constexpr (MODE == MODE_F32) {
          ((float*)C0)[(size_t)m * ldc + n] = val;
        } else if constexpr (MODE == MODE_DUAL) {
          ((float*)C0)[(size_t)m * ldc + n] = val;
          ((u16*)C1)[(size_t)m * ldc + n] = f2bs(val);
        } else if constexpr (MODE == MODE_QKV) {
          const int b = m >> 10, s = m & 1023;
          const u16 outv = f2bs(val);
          const int h = (n & 255) >> 6, d = n & 63;
          if (n < 256)
            ((u16*)C0)[(((size_t)(b * 4 + h)) * 1024 + s) * 64 + d] = outv;  // q [BH,S,dh]
          else if (n < 512)
            ((u16*)C1)[(((size_t)(b * 4 + h)) * 1024 + s) * 64 + d] = outv;  // k [BH,S,dh]
          else
            ((u16*)C2)[(((size_t)(b * 4 + h)) * 64 + d) * 1024 + s] = outv;  // v^T [BH,dh,S]
        }
      }
    }
  }
}

// ---------------------------------------------------------------------------
// Flash attention: one block per (q-tile 128, pair). 4 waves x 32 q-rows.
// ---------------------------------------------------------------------------
__global__ __launch_bounds__(256) void attn_k(
    const u16* __restrict__ q_s,  // [128,1024,64]
    const u16* __restrict__ k_s,  // [128,1024,64]
    const u16* __restrict__ v_t,  // [128,64,1024]
    u16* __restrict__ o16)        // [32768,256] merged
{
  constexpr int LQ = 72, LV = 136, LP = 136;
  __shared__ __align__(16) u16 Qs[128 * LQ];
  __shared__ __align__(16) u16 Ks[128 * LQ];
  __shared__ __align__(16) u16 Vt[64 * LV];
  __shared__ __align__(16) u16 Ps[128 * LP];
  const int tid = threadIdx.x;
  const int w = tid >> 6, lane = tid & 63;
  const int r16 = lane & 15, quad = lane >> 4;
  const int p = blockIdx.y;
  const int q0 = blockIdx.x * 128;
  const u16* qg = q_s + ((size_t)p * 1024 + q0) * 64;
  const u16* kg = k_s + (size_t)p * 65536;
  const u16* vg = v_t + (size_t)p * 65536;

#pragma unroll
  for (int it = 0; it < 4; ++it) {
    const int idx = it * 256 + tid;
    const int row = idx >> 3, c8 = (idx & 7) * 8;
    *(uint4*)&Qs[row * LQ + c8] = *(const uint4*)(qg + (size_t)row * 64 + c8);
    *(uint4*)&Ks[row * LQ + c8] = *(const uint4*)(kg + (size_t)row * 64 + c8);
  }
#pragma unroll
  for (int it = 0; it < 4; ++it) {
    const int idx = it * 256 + tid;
    const int row = idx >> 4, c8 = (idx & 15) * 8;
    *(uint4*)&Vt[row * LV + c8] = *(const uint4*)(vg + (size_t)row * 1024 + c8);
  }
  __syncthreads();

  short8 aq[2][2];
#pragma unroll
  for (int i = 0; i < 2; ++i)
#pragma unroll
    for (int kc = 0; kc < 2; ++kc)
      aq[i][kc] = *(const short8*)&Qs[(w * 32 + i * 16 + r16) * LQ + kc * 32 + quad * 8];

  floatx4 o[2][4] = {};
  float mr[2][4], l[2][4];
#pragma unroll
  for (int i = 0; i < 2; ++i)
#pragma unroll
    for (int q = 0; q < 4; ++q) { mr[i][q] = -3e38f; l[i][q] = 0.f; }

  for (int kt = 0; kt < 8; ++kt) {
    uint4 kpre[4], vpre[4];
    if (kt < 7) {
      const u16* kgn = kg + (size_t)(kt + 1) * 128 * 64;
#pragma unroll
      for (int it = 0; it < 4; ++it) {
        const int idx = it * 256 + tid;
        kpre[it] = *(const uint4*)(kgn + (size_t)(idx >> 3) * 64 + (idx & 7) * 8);
        vpre[it] = *(const uint4*)(vg + (size_t)(idx >> 4) * 1024 + (kt + 1) * 128 + (idx & 15) * 8);
      }
    }
    floatx4 s[2][8] = {};
#pragma unroll
    for (int kc = 0; kc < 2; ++kc) {
#pragma unroll
      for (int f = 0; f < 8; ++f) {
        const short8 bk = *(const short8*)&Ks[(f * 16 + r16) * LQ + kc * 32 + quad * 8];
#pragma unroll
        for (int i = 0; i < 2; ++i)
          s[i][f] = __builtin_amdgcn_mfma_f32_16x16x32_bf16(aq[i][kc], bk, s[i][f], 0, 0, 0);
      }
    }
#pragma unroll
    for (int i = 0; i < 2; ++i) {
      float mt[4] = {-3e38f, -3e38f, -3e38f, -3e38f};
#pragma unroll
      for (int f = 0; f < 8; ++f)
#pragma unroll
        for (int q = 0; q < 4; ++q) {
          s[i][f][q] *= 0.125f;
          mt[q] = fmaxf(mt[q], s[i][f][q]);
        }
#pragma unroll
      for (int off = 8; off > 0; off >>= 1)
#pragma unroll
        for (int q = 0; q < 4; ++q) mt[q] = fmaxf(mt[q], __shfl_xor(mt[q], off));
      float al[4], rs[4] = {};
#pragma unroll
      for (int q = 0; q < 4; ++q) {
        const float mn = fmaxf(mr[i][q], mt[q]);
        al[q] = __expf(mr[i][q] - mn);
        mr[i][q] = mn;
      }
#pragma unroll
      for (int f = 0; f < 8; ++f)
#pragma unroll
        for (int q = 0; q < 4; ++q) {
          const float pv = __expf(s[i][f][q] - mr[i][q]);
          s[i][f][q] = pv;
          rs[q] += pv;
        }
#pragma unroll
      for (int off = 8; off > 0; off >>= 1)
#pragma unroll
        for (int q = 0; q < 4; ++q) rs[q] += __shfl_xor(rs[q], off);
#pragma unroll
      for (int q = 0; q < 4; ++q) l[i][q] = l[i][q] * al[q] + rs[q];
#pragma unroll
      for (int n = 0; n < 4; ++n)
#pragma unroll
        for (int q = 0; q < 4; ++q) o[i][n][q] *= al[q];
#pragma unroll
      for (int f = 0; f < 8; ++f)
#pragma unroll
        for (int q = 0; q < 4; ++q)
          Ps[(w * 32 + i * 16 + quad * 4 + q) * LP + f * 16 + r16] = f2bs(s[i][f][q]);
    }
#pragma unroll
    for (int kc = 0; kc < 4; ++kc) {
      short8 ap[2];
#pragma unroll
      for (int i = 0; i < 2; ++i)
        ap[i] = *(const short8*)&Ps[(w * 32 + i * 16 + r16) * LP + kc * 32 + quad * 8];
#pragma unroll
      for (int n = 0; n < 4; ++n) {
        const short8 bv = *(const short8*)&Vt[(n * 16 + r16) * LV + kc * 32 + quad * 8];
#pragma unroll
        for (int i = 0; i < 2; ++i)
          o[i][n] = __builtin_amdgcn_mfma_f32_16x16x32_bf16(ap[i], bv, o[i][n], 0, 0, 0);
      }
    }
    __syncthreads();
    if (kt < 7) {
#pragma unroll
      for (int it = 0; it < 4; ++it) {
        const int idx = it * 256 + tid;
        *(uint4*)&Ks[(idx >> 3) * LQ + (idx & 7) * 8] = kpre[it];
        *(uint4*)&Vt[(idx >> 4) * LV + (idx & 15) * 8] = vpre[it];
      }
      __syncthreads();
    }
  }
  const int bb = p >> 2, hh = p & 3;
#pragma unroll
  for (int i = 0; i < 2; ++i)
#pragma unroll
    for (int q = 0; q < 4; ++q) {
      const float inv = 1.f / l[i][q];
      const int srow = q0 + w * 32 + i * 16 + quad * 4 + q;
#pragma unroll
      for (int n = 0; n < 4; ++n)
        o16[((size_t)bb * 1024 + srow) * 256 + hh * 64 + n * 16 + r16] =
            f2bs(o[i][n][q] * inv);
    }
}

// ---------------------------------------------------------------------------
// Fused residual-add + LayerNorm over 256 fp32; writes fp32 and/or bf16.
// ---------------------------------------------------------------------------
__global__ __launch_bounds__(256) void ln_k(const float* __restrict__ x,
                                            const float* __restrict__ add,
                                            const float* __restrict__ g,
                                            const float* __restrict__ bta,
                                            float* __restrict__ y32,
                                            u16* __restrict__ y16) {
  const int row = blockIdx.x * 4 + (threadIdx.x >> 6);
  const int lane = threadIdx.x & 63;
  const size_t base = (size_t)row * 256 + lane * 4;
  const float4 xv = *(const float4*)(x + base);
  const float4 av = *(const float4*)(add + base);
  float sv[4] = {xv.x + av.x, xv.y + av.y, xv.z + av.z, xv.w + av.w};
  float sum = sv[0] + sv[1] + sv[2] + sv[3];
#pragma unroll
  for (int off = 32; off > 0; off >>= 1) sum += __shfl_xor(sum, off);
  const float mean = sum * (1.f / 256.f);
  float var = 0.f;
  float d[4];
#pragma unroll
  for (int i = 0; i < 4; ++i) { d[i] = sv[i] - mean; var += d[i] * d[i]; }
#pragma unroll
  for (int off = 32; off > 0; off >>= 1) var += __shfl_xor(var, off);
  var *= (1.f / 256.f);
  const float inv = 1.f / sqrtf(var + 1e-5f);
  float yv[4];
#pragma unroll
  for (int i = 0; i < 4; ++i)
    yv[i] = d[i] * inv * g[lane * 4 + i] + bta[lane * 4 + i];
  if (y32) *(float4*)(y32 + base) = make_float4(yv[0], yv[1], yv[2], yv[3]);
  if (y16) {
    const u32 p0 = (u32)f2bs(yv[0]) | ((u32)f2bs(yv[1]) << 16);
    const u32 p1 = (u32)f2bs(yv[2]) | ((u32)f2bs(yv[3]) << 16);
    *(uint2*)(y16 + base) = make_uint2(p0, p1);
  }
}

// ---------------------------------------------------------------------------
extern "C" void kernel_launch(void* const* d_in, const int* in_sizes, int n_in,
                              void* d_out, int out_size, void* d_ws,
                              size_t ws_size, hipStream_t stream) {
  (void)in_sizes; (void)n_in; (void)out_size; (void)ws_size;
  const float* x     = (const float*)d_in[0];
  const float* Win   = (const float*)d_in[1];
  const float* Wres  = (const float*)d_in[2];
  const float* Wread = (const float*)d_in[3];
  const float* bread = (const float*)d_in[4];
  const float* Wqkv  = (const float*)d_in[5];
  const float* bqkv  = (const float*)d_in[6];
  const float* Wo    = (const float*)d_in[7];
  const float* bo    = (const float*)d_in[8];
  const float* g1    = (const float*)d_in[9];
  const float* b1    = (const float*)d_in[10];
  const float* g2    = (const float*)d_in[11];
  const float* b2    = (const float*)d_in[12];
  const float* W1    = (const float*)d_in[13];
  const float* c1    = (const float*)d_in[14];
  const float* W2    = (const float*)d_in[15];
  const float* c2    = (const float*)d_in[16];

  char* ws = (char*)d_ws;
  size_t off = 0;
  auto carve = [&](size_t bytes) {
    char* p = ws + off;
    off += (bytes + 255) & ~(size_t)255;
    return p;
  };
  u16* z      = (u16*)carve((size_t)32 * 1024 * 512 * 2);
  u16* wrd16  = (u16*)carve((size_t)256 * 512 * 2);
  u16* wqkv16 = (u16*)carve((size_t)2 * 768 * 256 * 2);
  u16* wo16   = (u16*)carve((size_t)2 * 256 * 256 * 2);
  u16* w116   = (u16*)carve((size_t)2 * 1024 * 256 * 2);
  u16* w216   = (u16*)carve((size_t)2 * 256 * 1024 * 2);
  u16* q_s    = (u16*)carve((size_t)128 * 1024 * 64 * 2);
  u16* k_s    = (u16*)carve((size_t)128 * 1024 * 64 * 2);
  u16* v_t    = (u16*)carve((size_t)128 * 64 * 1024 * 2);
  float* h32  = (float*)carve((size_t)32768 * 256 * 4);
  float* lin  = (float*)carve((size_t)32768 * 256 * 4);
  u16* h16    = (u16*)carve((size_t)32768 * 256 * 2);
  u16* ff1    = (u16*)carve((size_t)32768 * 1024 * 2);
  u16* o16    = h16;          // attention output reuses h16
  float* inp  = (float*)ff1;  // precomputed input currents (dead before ff1)

  cvt_all_k<<<dim3(6656), dim3(256), 0, stream>>>(Wread, Wqkv, Wo, W1, W2,
                                                  wrd16, wqkv16, wo16, w116,
                                                  w216);
  inp_k<<<dim3(32768), dim3(512), 0, stream>>>(x, Win, inp);
  reservoir_k<<<dim3(32), dim3(64), 0, stream>>>(inp, Wres, z);

  // readout: h = z @ Wread^T + bread  (dual fp32 + bf16)
  gemm_bt<2, 2, MODE_DUAL><<<dim3(2, 256, 1), dim3(256), 0, stream>>>(
      z, wrd16, bread, h32, h16, nullptr, 512, 512, 512, 256, 0, 0, 0, 1.0f, 0);

  for (int l = 0; l < 2; ++l) {
    gemm_bt<2, 2, MODE_QKV><<<dim3(6, 256, 1), dim3(256), 0, stream>>>(
        h16, wqkv16 + (size_t)l * 196608, bqkv + l * 768, q_s, k_s, v_t, 256,
        256, 256, 0, 0, 0, 0, 1.0f, 0);
    attn_k<<<dim3(8, 128), dim3(256), 0, stream>>>(q_s, k_s, v_t, o16);
    gemm_bt<2, 2, MODE_F32><<<dim3(2, 256, 1), dim3(256), 0, stream>>>(
        o16, wo16 + (size_t)l * 65536, bo + l * 256, lin, nullptr, nullptr,
        256, 256, 256, 256, 0, 0, 0, 1.0f, 0);
    ln_k<<<dim3(8192), dim3(256), 0, stream>>>(h32, lin, g1 + l * 256,
                                               b1 + l * 256, h32, h16);
    gemm_bt<2, 2, MODE_BF16><<<dim3(8, 256, 1), dim3(256), 0, stream>>>(
        h16, w116 + (size_t)l * 262144, c1 + l * 1024, ff1, nullptr, nullptr,
        256, 256, 256, 1024, 0, 0, 0, 1.0f, 1);
    gemm_bt<2, 2, MODE_F32><<<dim3(2, 256, 1), dim3(256), 0, stream>>>(
        ff1, w216 + (size_t)l * 262144, c2 + l * 256, lin, nullptr, nullptr,
        1024, 1024, 1024, 256, 0, 0, 0, 1.0f, 0);
    float* y32 = (l == 1) ? (float*)d_out : h32;
    u16* y16 = (l == 1) ? nullptr : h16;
    ln_k<<<dim3(8192), dim3(256), 0, stream>>>(h32, lin, g2 + l * 256,
                                               b2 + l * 256, y32, y16);
  }
}

// Round 12
// 1341.902 us; speedup vs baseline: 1.0879x; 1.0229x over previous
//
#include <hip/hip_runtime.h>
#include <stdint.h>

using short8  = __attribute__((ext_vector_type(8))) short;
using floatx4 = __attribute__((ext_vector_type(4))) float;

typedef unsigned short u16;
typedef unsigned int u32;
typedef unsigned long long u64;

#define AS1(p) ((const __attribute__((address_space(1))) void*)(p))
#define AS3(p) ((__attribute__((address_space(3))) void*)(p))

__device__ __forceinline__ float bs2f(u16 u) { return __uint_as_float(((u32)u) << 16); }
__device__ __forceinline__ u16 f2bs(float f) {
  u32 x = __float_as_uint(f);
  x += 0x7FFFu + ((x >> 16) & 1u);   // RNE
  return (u16)(x >> 16);
}

// ---------------------------------------------------------------------------
// fp32 -> bf16 conversion for all 5 weight tensors in ONE launch.
// ---------------------------------------------------------------------------
__global__ __launch_bounds__(256) void cvt_all_k(
    const float* __restrict__ s0, const float* __restrict__ s1,
    const float* __restrict__ s2, const float* __restrict__ s3,
    const float* __restrict__ s4, u16* __restrict__ d0, u16* __restrict__ d1,
    u16* __restrict__ d2, u16* __restrict__ d3, u16* __restrict__ d4) {
  const int i = blockIdx.x * 256 + threadIdx.x;
  if (i < 131072)        d0[i] = f2bs(s0[i]);
  else if (i < 524288)   d1[i - 131072] = f2bs(s1[i - 131072]);
  else if (i < 655360)   d2[i - 524288] = f2bs(s2[i - 524288]);
  else if (i < 1179648)  d3[i - 655360] = f2bs(s3[i - 655360]);
  else                   d4[i - 1179648] = f2bs(s4[i - 1179648]);
}

// ---------------------------------------------------------------------------
// inp[row, idx(r)] = sum_k x[row, k] * Win[k, r]  (fp32, fmaf k-ascending),
// stored in the reservoir's interleaved LDS-staging layout.
// ---------------------------------------------------------------------------
__global__ __launch_bounds__(512) void inp_k(const float* __restrict__ x,
                                             const float* __restrict__ Win,
                                             float* __restrict__ inp) {
  const int row = blockIdx.x;
  const int r = threadIdx.x;
  const float* xr = x + (size_t)row * 8;
  float s = 0.f;
#pragma unroll
  for (int k = 0; k < 8; ++k) s = fmaf(Win[k * 512 + r], xr[k], s);
  const int c = r >> 3, j = r & 7;
  const int idx = (j < 4) ? (c * 4 + j) : (256 + c * 4 + (j - 4));
  inp[(size_t)row * 512 + idx] = s;
}

// ---------------------------------------------------------------------------
// LIF reservoir (frozen at the r11 design — measured single-wave floor).
// ---------------------------------------------------------------------------
__global__ __launch_bounds__(64, 1) void reservoir_k(
    const float* __restrict__ inp,  // [32,1024,512] fp32, interleaved layout
    const float* __restrict__ Wres, // [512,512]
    u16* __restrict__ zout)         // [32,1024,512] bf16 (0.0/1.0, exact)
{
  const int b = blockIdx.x;
  const int c = threadIdx.x & 63;
  __shared__ __align__(16) float s_in[2][4096];   // 2 x (8 steps x 512)
  const float* ib = inp + (size_t)b * 524288;
  u16* zb = zout + (size_t)b * 524288 + c * 8;
  float v[8] = {}, ci[8] = {}, rec[8] = {};
  u32 pz = 0;
#pragma unroll
  for (int i = 0; i < 16; ++i)
    __builtin_amdgcn_global_load_lds(AS1(ib + i * 256 + c * 4),
                                     AS3(&s_in[0][i * 256 + c * 4]), 16, 0, 0);
#pragma unroll
  for (int i = 0; i < 16; ++i)
    __builtin_amdgcn_global_load_lds(AS1(ib + 4096 + i * 256 + c * 4),
                                     AS3(&s_in[1][i * 256 + c * 4]), 16, 0, 0);
  for (int g = 0; g < 128; ++g) {
    const int buf = g & 1;
    if (g < 126) __builtin_amdgcn_s_waitcnt(0x4F70);  // vmcnt(16)
    else         __builtin_amdgcn_s_waitcnt(0x0F70);  // vmcnt(0)
    asm volatile("" ::: "memory");
#pragma unroll
    for (int u = 0; u < 8; ++u) {
      const int t = g * 8 + u;
      const float4 xa = *(const float4*)&s_in[buf][u * 512 + c * 4];
      const float4 xc = *(const float4*)&s_in[buf][u * 512 + 256 + c * 4];
      const float in[8] = {xa.x, xa.y, xa.z, xa.w, xc.x, xc.y, xc.z, xc.w};
      u32 nzb = 0;
      u32 zw[4];
#pragma unroll
      for (int j = 0; j < 8; ++j) {
        const float vdec = __fadd_rn(v[j], __fmul_rn(0.004f, __fadd_rn(-v[j], ci[j])));
        const int zc = (__fadd_rn(vdec, -0.1f) > 0.f) ? 1 : 0;
        v[j] = zc ? 0.f : vdec;
        nzb |= (u32)zc << j;
        ci[j] = __fadd_rn(__fmul_rn(ci[j], 0.8f), __fadd_rn(in[j], rec[j]));
        if (j & 1) zw[j >> 1] |= zc ? 0x3F800000u : 0u;
        else       zw[j >> 1]  = zc ? 0x3F80u : 0u;
      }
      *(uint4*)(zb + (size_t)t * 512) = make_uint4(zw[0], zw[1], zw[2], zw[3]);
      const u64 anyt = __ballot((nzb ^ pz) != 0);
      if (anyt) {
#pragma unroll
        for (int j = 0; j < 8; ++j) {
          const u64 nm = __ballot((nzb >> j) & 1);
          const u64 pm = __ballot((pz >> j) & 1);
          u64 on   = nm & ~pm;
          u64 offm = pm & ~nm;
          while (on) {
            const int cc = __builtin_ctzll(on); on &= on - 1;
            const float* wr = Wres + ((size_t)(cc * 8 + j) << 9) + c * 8;
            const float4 w0 = *(const float4*)wr;
            const float4 w1 = *(const float4*)(wr + 4);
            rec[0] += w0.x; rec[1] += w0.y; rec[2] += w0.z; rec[3] += w0.w;
            rec[4] += w1.x; rec[5] += w1.y; rec[6] += w1.z; rec[7] += w1.w;
          }
          while (offm) {
            const int cc = __builtin_ctzll(offm); offm &= offm - 1;
            const float* wr = Wres + ((size_t)(cc * 8 + j) << 9) + c * 8;
            const float4 w0 = *(const float4*)wr;
            const float4 w1 = *(const float4*)(wr + 4);
            rec[0] -= w0.x; rec[1] -= w0.y; rec[2] -= w0.z; rec[3] -= w0.w;
            rec[4] -= w1.x; rec[5] -= w1.y; rec[6] -= w1.z; rec[7] -= w1.w;
          }
        }
      }
      pz = nzb;
    }
    asm volatile("" ::: "memory");
    if (g + 2 < 128) {
      const float* gt = ib + (size_t)(g + 2) * 4096;
#pragma unroll
      for (int i = 0; i < 16; ++i)
        __builtin_amdgcn_global_load_lds(AS1(gt + i * 256 + c * 4),
                                         AS3(&s_in[buf][i * 256 + c * 4]), 16, 0, 0);
    }
  }
}

// ---------------------------------------------------------------------------
// Generic bf16 MFMA GEMM: C = epilogue(A @ B^T * scale + bias)
// MODE_QKV additionally pre-scales q outputs by 0.125*log2(e) so attention
// runs in the exp2 domain with no per-score scaling.
// ---------------------------------------------------------------------------
enum { MODE_BF16 = 0, MODE_F32 = 1, MODE_DUAL = 2, MODE_QKV = 3 };

template <int WM, int WN, int MODE>
__global__ __launch_bounds__(WM * WN * 64) void gemm_bt(
    const u16* __restrict__ A, const u16* __restrict__ B,
    const float* __restrict__ bias, void* __restrict__ C0,
    void* __restrict__ C1, void* __restrict__ C2, int K, int lda, int ldb,
    int ldc, long long sA, long long sB, long long sC, float scale, int relu)
{
  constexpr int BM = WM * 64, BN = WN * 64, BK = 32;
  constexpr int NT = WM * WN * 64;
  constexpr int CA = BM * 4 / NT, CB = BN * 4 / NT;
  __shared__ __align__(16) u16 As[BM * BK];
  __shared__ __align__(16) u16 Bs[BN * BK];
  const int tid = threadIdx.x;
  const int bz = blockIdx.z;
  const u16* Ab = A + (size_t)bz * sA + (size_t)blockIdx.y * BM * lda;
  const u16* Bb = B + (size_t)bz * sB + (size_t)blockIdx.x * BN * ldb;
  const int wavei = tid >> 6, lane = tid & 63;
  const int r16 = lane & 15, quad = lane >> 4;
  const int wm = (wavei % WM) * 64, wn = (wavei / WM) * 64;
  floatx4 acc[4][4] = {};
  for (int k0 = 0; k0 < K; k0 += BK) {
#pragma unroll
    for (int c = 0; c < CA; ++c) {
      const int idx = c * NT + tid;
      const int row = idx >> 2, kc = (idx & 3) << 3;
      __builtin_amdgcn_global_load_lds(AS1(Ab + (size_t)row * lda + k0 + kc),
                                       AS3(As + idx * 8), 16, 0, 0);
    }
#pragma unroll
    for (int c = 0; c < CB; ++c) {
      const int idx = c * NT + tid;
      const int row = idx >> 2, kc = (idx & 3) << 3;
      __builtin_amdgcn_global_load_lds(AS1(Bb + (size_t)row * ldb + k0 + kc),
                                       AS3(Bs + idx * 8), 16, 0, 0);
    }
    __syncthreads();
    short8 af[4], bfr[4];
#pragma unroll
    for (int i = 0; i < 4; ++i)
      af[i] = *(const short8*)&As[(wm + i * 16 + r16) * BK + quad * 8];
#pragma unroll
    for (int i = 0; i < 4; ++i)
      bfr[i] = *(const short8*)&Bs[(wn + i * 16 + r16) * BK + quad * 8];
#pragma unroll
    for (int i = 0; i < 4; ++i)
#pragma unroll
      for (int j = 0; j < 4; ++j)
        acc[i][j] = __builtin_amdgcn_mfma_f32_16x16x32_bf16(af[i], bfr[j], acc[i][j], 0, 0, 0);
    __syncthreads();
  }
#pragma unroll
  for (int i = 0; i < 4; ++i) {
#pragma unroll
    for (int j = 0; j < 4; ++j) {
#pragma unroll
      for (int q = 0; q < 4; ++q) {
        const int m = blockIdx.y * BM + wm + i * 16 + quad * 4 + q;
        const int n = blockIdx.x * BN + wn + j * 16 + r16;
        float val = acc[i][j][q] * scale;
        if (bias) val += bias[n];
        if (relu) val = fmaxf(val, 0.f);
        if constexpr (MODE == MODE_BF16) {
          ((u16*)C0)[(size_t)bz * sC + (size_t)m * ldc + n] = f2bs(val);
        } else if constexpr (MODE == MODE_F32) {
          ((float*)C0)[(size_t)m * ldc + n] = val;
        } else if constexpr (MODE == MODE_DUAL) {
          ((float*)C0)[(size_t)m * ldc + n] = val;
          ((u16*)C1)[(size_t)m * ldc + n] = f2bs(val);
        } else if constexpr (MODE == MODE_QKV) {
          const int b = m >> 10, s = m & 1023;
          const int h = (n & 255) >> 6, d = n & 63;
          if (n < 256) {
            val *= 0.18033688f;   // 0.125 * log2(e): exp2-domain attention
            ((u16*)C0)[(((size_t)(b * 4 + h)) * 1024 + s) * 64 + d] = f2bs(val);
          } else if (n < 512) {
            ((u16*)C1)[(((size_t)(b * 4 + h)) * 1024 + s) * 64 + d] = f2bs(val);
          } else {
            ((u16*)C2)[(((size_t)(b * 4 + h)) * 64 + d) * 1024 + s] = f2bs(val);
          }
        }
      }
    }
  }
}

// ---------------------------------------------------------------------------
// Fused GEMM + residual-add + LayerNorm (full 256-wide rows per block).
// y = LN( A@B^T + bias + res ).  BM=64, BN=256, 4 waves, K in {256,1024}.
// Single-pass mean/var (E[x^2]-m^2), shfl r16-reduce + LDS cross-wave.
// ---------------------------------------------------------------------------
__global__ __launch_bounds__(256) void gemm_ln_k(
    const u16* __restrict__ A, const u16* __restrict__ B,
    const float* __restrict__ bias, const float* __restrict__ res,
    const float* __restrict__ gamma, const float* __restrict__ beta,
    float* __restrict__ y32, u16* __restrict__ y16, int K)
{
  constexpr int BM = 64, BN = 256, BK = 32, NT = 256;
  __shared__ __align__(16) u16 As[BM * BK];
  __shared__ __align__(16) u16 Bs[BN * BK];
  __shared__ float rsum[64][4];
  __shared__ float rsq[64][4];
  const int tid = threadIdx.x;
  const u16* Ab = A + (size_t)blockIdx.y * BM * K;   // lda == K
  const int wavei = tid >> 6, lane = tid & 63;
  const int r16 = lane & 15, quad = lane >> 4;
  const int wn = wavei * 64;
  floatx4 acc[4][4] = {};
  for (int k0 = 0; k0 < K; k0 += BK) {
    {
      const int row = tid >> 2, kc = (tid & 3) << 3;
      __builtin_amdgcn_global_load_lds(AS1(Ab + (size_t)row * K + k0 + kc),
                                       AS3(As + tid * 8), 16, 0, 0);
    }
#pragma unroll
    for (int c = 0; c < 4; ++c) {
      const int idx = c * NT + tid;
      const int row = idx >> 2, kc = (idx & 3) << 3;
      __builtin_amdgcn_global_load_lds(AS1(B + (size_t)row * K + k0 + kc),
                                       AS3(Bs + idx * 8), 16, 0, 0);
    }
    __syncthreads();
    short8 af[4], bfr[4];
#pragma unroll
    for (int i = 0; i < 4; ++i)
      af[i] = *(const short8*)&As[(i * 16 + r16) * BK + quad * 8];
#pragma unroll
    for (int j = 0; j < 4; ++j)
      bfr[j] = *(const short8*)&Bs[(wn + j * 16 + r16) * BK + quad * 8];
#pragma unroll
    for (int i = 0; i < 4; ++i)
#pragma unroll
      for (int j = 0; j < 4; ++j)
        acc[i][j] = __builtin_amdgcn_mfma_f32_16x16x32_bf16(af[i], bfr[j], acc[i][j], 0, 0, 0);
    __syncthreads();
  }
  // epilogue: add bias + residual (in place in acc), accumulate row stats
  float ps[4][4] = {}, pq[4][4] = {};
#pragma unroll
  for (int i = 0; i < 4; ++i)
#pragma unroll
    for (int j = 0; j < 4; ++j)
#pragma unroll
      for (int q = 0; q < 4; ++q) {
        const int m = blockIdx.y * 64 + i * 16 + quad * 4 + q;
        const int n = wn + j * 16 + r16;
        const float val = acc[i][j][q] + bias[n] + res[(size_t)m * 256 + n];
        acc[i][j][q] = val;
        ps[i][q] += val;
        pq[i][q] += val * val;
      }
#pragma unroll
  for (int off = 1; off < 16; off <<= 1)
#pragma unroll
    for (int i = 0; i < 4; ++i)
#pragma unroll
      for (int q = 0; q < 4; ++q) {
        ps[i][q] += __shfl_xor(ps[i][q], off);
        pq[i][q] += __shfl_xor(pq[i][q], off);
      }
  if (r16 == 0) {
#pragma unroll
    for (int i = 0; i < 4; ++i)
#pragma unroll
      for (int q = 0; q < 4; ++q) {
        rsum[i * 16 + quad * 4 + q][wavei] = ps[i][q];
        rsq[i * 16 + quad * 4 + q][wavei] = pq[i][q];
      }
  }
  __syncthreads();
#pragma unroll
  for (int i = 0; i < 4; ++i)
#pragma unroll
    for (int q = 0; q < 4; ++q) {
      const int rl = i * 16 + quad * 4 + q;
      const float4 s4 = *(const float4*)rsum[rl];
      const float4 q4 = *(const float4*)rsq[rl];
      const float mean = (s4.x + s4.y + s4.z + s4.w) * (1.f / 256.f);
      const float var = (q4.x + q4.y + q4.z + q4.w) * (1.f / 256.f) - mean * mean;
      const float inv = 1.f / sqrtf(var + 1e-5f);
      const int m = blockIdx.y * 64 + rl;
#pragma unroll
      for (int j = 0; j < 4; ++j) {
        const int n = wn + j * 16 + r16;
        const float yv = (acc[i][j][q] - mean) * inv * gamma[n] + beta[n];
        y32[(size_t)m * 256 + n] = yv;
        if (y16) y16[(size_t)m * 256 + n] = f2bs(yv);
      }
    }
}

// ---------------------------------------------------------------------------
// Flash attention (exp2 domain — q pre-scaled by 0.125*log2e in QKV).
// One block per (q-tile 128, pair). 4 waves x 32 q-rows.
// ---------------------------------------------------------------------------
__global__ __launch_bounds__(256) void attn_k(
    const u16* __restrict__ q_s,  // [128,1024,64]
    const u16* __restrict__ k_s,  // [128,1024,64]
    const u16* __restrict__ v_t,  // [128,64,1024]
    u16* __restrict__ o16)        // [32768,256] merged
{
  constexpr int LQ = 72, LV = 136, LP = 136;
  __shared__ __align__(16) u16 Qs[128 * LQ];
  __shared__ __align__(16) u16 Ks[128 * LQ];
  __shared__ __align__(16) u16 Vt[64 * LV];
  __shared__ __align__(16) u16 Ps[128 * LP];
  const int tid = threadIdx.x;
  const int w = tid >> 6, lane = tid & 63;
  const int r16 = lane & 15, quad = lane >> 4;
  const int p = blockIdx.y;
  const int q0 = blockIdx.x * 128;
  const u16* qg = q_s + ((size_t)p * 1024 + q0) * 64;
  const u16* kg = k_s + (size_t)p * 65536;
  const u16* vg = v_t + (size_t)p * 65536;

#pragma unroll
  for (int it = 0; it < 4; ++it) {
    const int idx = it * 256 + tid;
    const int row = idx >> 3, c8 = (idx & 7) * 8;
    *(uint4*)&Qs[row * LQ + c8] = *(const uint4*)(qg + (size_t)row * 64 + c8);
    *(uint4*)&Ks[row * LQ + c8] = *(const uint4*)(kg + (size_t)row * 64 + c8);
  }
#pragma unroll
  for (int it = 0; it < 4; ++it) {
    const int idx = it * 256 + tid;
    const int row = idx >> 4, c8 = (idx & 15) * 8;
    *(uint4*)&Vt[row * LV + c8] = *(const uint4*)(vg + (size_t)row * 1024 + c8);
  }
  __syncthreads();

  short8 aq[2][2];
#pragma unroll
  for (int i = 0; i < 2; ++i)
#pragma unroll
    for (int kc = 0; kc < 2; ++kc)
      aq[i][kc] = *(const short8*)&Qs[(w * 32 + i * 16 + r16) * LQ + kc * 32 + quad * 8];

  floatx4 o[2][4] = {};
  float mr[2][4], l[2][4];
#pragma unroll
  for (int i = 0; i < 2; ++i)
#pragma unroll
    for (int q = 0; q < 4; ++q) { mr[i][q] = -3e38f; l[i][q] = 0.f; }

  for (int kt = 0; kt < 8; ++kt) {
    uint4 kpre[4], vpre[4];
    if (kt < 7) {
      const u16* kgn = kg + (size_t)(kt + 1) * 128 * 64;
#pragma unroll
      for (int it = 0; it < 4; ++it) {
        const int idx = it * 256 + tid;
        kpre[it] = *(const uint4*)(kgn + (size_t)(idx >> 3) * 64 + (idx & 7) * 8);
        vpre[it] = *(const uint4*)(vg + (size_t)(idx >> 4) * 1024 + (kt + 1) * 128 + (idx & 15) * 8);
      }
    }
    floatx4 s[2][8] = {};
#pragma unroll
    for (int kc = 0; kc < 2; ++kc) {
#pragma unroll
      for (int f = 0; f < 8; ++f) {
        const short8 bk = *(const short8*)&Ks[(f * 16 + r16) * LQ + kc * 32 + quad * 8];
#pragma unroll
        for (int i = 0; i < 2; ++i)
          s[i][f] = __builtin_amdgcn_mfma_f32_16x16x32_bf16(aq[i][kc], bk, s[i][f], 0, 0, 0);
      }
    }
#pragma unroll
    for (int i = 0; i < 2; ++i) {
      float mt[4] = {-3e38f, -3e38f, -3e38f, -3e38f};
#pragma unroll
      for (int f = 0; f < 8; ++f)
#pragma unroll
        for (int q = 0; q < 4; ++q) mt[q] = fmaxf(mt[q], s[i][f][q]);
#pragma unroll
      for (int off = 8; off > 0; off >>= 1)
#pragma unroll
        for (int q = 0; q < 4; ++q) mt[q] = fmaxf(mt[q], __shfl_xor(mt[q], off));
      float al[4], rs[4] = {};
#pragma unroll
      for (int q = 0; q < 4; ++q) {
        const float mn = fmaxf(mr[i][q], mt[q]);
        al[q] = exp2f(mr[i][q] - mn);
        mr[i][q] = mn;
      }
#pragma unroll
      for (int f = 0; f < 8; ++f)
#pragma unroll
        for (int q = 0; q < 4; ++q) {
          const float pv = exp2f(s[i][f][q] - mr[i][q]);
          s[i][f][q] = pv;
          rs[q] += pv;
        }
#pragma unroll
      for (int off = 8; off > 0; off >>= 1)
#pragma unroll
        for (int q = 0; q < 4; ++q) rs[q] += __shfl_xor(rs[q], off);
#pragma unroll
      for (int q = 0; q < 4; ++q) l[i][q] = l[i][q] * al[q] + rs[q];
#pragma unroll
      for (int n = 0; n < 4; ++n)
#pragma unroll
        for (int q = 0; q < 4; ++q) o[i][n][q] *= al[q];
#pragma unroll
      for (int f = 0; f < 8; ++f)
#pragma unroll
        for (int q = 0; q < 4; ++q)
          Ps[(w * 32 + i * 16 + quad * 4 + q) * LP + f * 16 + r16] = f2bs(s[i][f][q]);
    }
#pragma unroll
    for (int kc = 0; kc < 4; ++kc) {
      short8 ap[2];
#pragma unroll
      for (int i = 0; i < 2; ++i)
        ap[i] = *(const short8*)&Ps[(w * 32 + i * 16 + r16) * LP + kc * 32 + quad * 8];
#pragma unroll
      for (int n = 0; n < 4; ++n) {
        const short8 bv = *(const short8*)&Vt[(n * 16 + r16) * LV + kc * 32 + quad * 8];
#pragma unroll
        for (int i = 0; i < 2; ++i)
          o[i][n] = __builtin_amdgcn_mfma_f32_16x16x32_bf16(ap[i], bv, o[i][n], 0, 0, 0);
      }
    }
    __syncthreads();
    if (kt < 7) {
#pragma unroll
      for (int it = 0; it < 4; ++it) {
        const int idx = it * 256 + tid;
        *(uint4*)&Ks[(idx >> 3) * LQ + (idx & 7) * 8] = kpre[it];
        *(uint4*)&Vt[(idx >> 4) * LV + (idx & 15) * 8] = vpre[it];
      }
      __syncthreads();
    }
  }
  const int bb = p >> 2, hh = p & 3;
#pragma unroll
  for (int i = 0; i < 2; ++i)
#pragma unroll
    for (int q = 0; q < 4; ++q) {
      const float inv = 1.f / l[i][q];
      const int srow = q0 + w * 32 + i * 16 + quad * 4 + q;
#pragma unroll
      for (int n = 0; n < 4; ++n)
        o16[((size_t)bb * 1024 + srow) * 256 + hh * 64 + n * 16 + r16] =
            f2bs(o[i][n][q] * inv);
    }
}

// ---------------------------------------------------------------------------
extern "C" void kernel_launch(void* const* d_in, const int* in_sizes, int n_in,
                              void* d_out, int out_size, void* d_ws,
                              size_t ws_size, hipStream_t stream) {
  (void)in_sizes; (void)n_in; (void)out_size; (void)ws_size;
  const float* x     = (const float*)d_in[0];
  const float* Win   = (const float*)d_in[1];
  const float* Wres  = (const float*)d_in[2];
  const float* Wread = (const float*)d_in[3];
  const float* bread = (const float*)d_in[4];
  const float* Wqkv  = (const float*)d_in[5];
  const float* bqkv  = (const float*)d_in[6];
  const float* Wo    = (const float*)d_in[7];
  const float* bo    = (const float*)d_in[8];
  const float* g1    = (const float*)d_in[9];
  const float* b1    = (const float*)d_in[10];
  const float* g2    = (const float*)d_in[11];
  const float* b2    = (const float*)d_in[12];
  const float* W1    = (const float*)d_in[13];
  const float* c1    = (const float*)d_in[14];
  const float* W2    = (const float*)d_in[15];
  const float* c2    = (const float*)d_in[16];

  char* ws = (char*)d_ws;
  size_t off = 0;
  auto carve = [&](size_t bytes) {
    char* p = ws + off;
    off += (bytes + 255) & ~(size_t)255;
    return p;
  };
  u16* z      = (u16*)carve((size_t)32 * 1024 * 512 * 2);
  u16* wrd16  = (u16*)carve((size_t)256 * 512 * 2);
  u16* wqkv16 = (u16*)carve((size_t)2 * 768 * 256 * 2);
  u16* wo16   = (u16*)carve((size_t)2 * 256 * 256 * 2);
  u16* w116   = (u16*)carve((size_t)2 * 1024 * 256 * 2);
  u16* w216   = (u16*)carve((size_t)2 * 256 * 1024 * 2);
  u16* q_s    = (u16*)carve((size_t)128 * 1024 * 64 * 2);
  u16* k_s    = (u16*)carve((size_t)128 * 1024 * 64 * 2);
  u16* v_t    = (u16*)carve((size_t)128 * 64 * 1024 * 2);
  float* h32  = (float*)carve((size_t)32768 * 256 * 4);
  u16* h16    = (u16*)carve((size_t)32768 * 256 * 2);
  u16* ff1    = (u16*)carve((size_t)32768 * 1024 * 2);
  u16* o16    = h16;          // attention output reuses h16
  float* inp  = (float*)ff1;  // precomputed input currents (dead before ff1)

  cvt_all_k<<<dim3(6656), dim3(256), 0, stream>>>(Wread, Wqkv, Wo, W1, W2,
                                                  wrd16, wqkv16, wo16, w116,
                                                  w216);
  inp_k<<<dim3(32768), dim3(512), 0, stream>>>(x, Win, inp);
  reservoir_k<<<dim3(32), dim3(64), 0, stream>>>(inp, Wres, z);

  // readout: h = z @ Wread^T + bread  (dual fp32 + bf16)
  gemm_bt<2, 2, MODE_DUAL><<<dim3(2, 256, 1), dim3(256), 0, stream>>>(
      z, wrd16, bread, h32, h16, nullptr, 512, 512, 512, 256, 0, 0, 0, 1.0f, 0);

  for (int l = 0; l < 2; ++l) {
    // qkv + scatter (q pre-scaled for exp2-domain attention)
    gemm_bt<2, 2, MODE_QKV><<<dim3(6, 256, 1), dim3(256), 0, stream>>>(
        h16, wqkv16 + (size_t)l * 196608, bqkv + l * 768, q_s, k_s, v_t, 256,
        256, 256, 0, 0, 0, 0, 1.0f, 0);
    attn_k<<<dim3(8, 128), dim3(256), 0, stream>>>(q_s, k_s, v_t, o16);
    // fused o-proj + residual + LN1  (h32, h16 updated in place)
    gemm_ln_k<<<dim3(1, 512), dim3(256), 0, stream>>>(
        o16, wo16 + (size_t)l * 65536, bo + l * 256, h32, g1 + l * 256,
        b1 + l * 256, h32, h16, 256);
    // FF1 + relu
    gemm_bt<2, 2, MODE_BF16><<<dim3(8, 256, 1), dim3(256), 0, stream>>>(
        h16, w116 + (size_t)l * 262144, c1 + l * 1024, ff1, nullptr, nullptr,
        256, 256, 256, 1024, 0, 0, 0, 1.0f, 1);
    // fused FF2 + residual + LN2 (final layer writes fp32 straight to d_out)
    float* y32 = (l == 1) ? (float*)d_out : h32;
    u16* y16 = (l == 1) ? nullptr : h16;
    gemm_ln_k<<<dim3(1, 512), dim3(256), 0, stream>>>(
        ff1, w216 + (size_t)l * 262144, c2 + l * 256, h32, g2 + l * 256,
        b2 + l * 256, y32, y16, 1024);
  }
}